// Round 8
// baseline (323.508 us; speedup 1.0000x reference)
//
#include <hip/hip_runtime.h>

// VQ-VAE quantization: z [16384 x 512] f32, codebook [8192 x 512] f32.
// out = concat(z_st [16384*512] f32, vq_loss [1] f32).
// bf16 MFMA GEMM (scores = z @ cb^T) with fused argmin epilogue, then
// fused candidate-reduce + gather + loss. d = ||e||^2 - 2 z.e.
//
// R2: XOR-swizzled LDS (bank conflicts 5e7 -> 0), gemm 280 -> 200 us.
// R3: gather_out atomic fix (16384 -> 1024 atomics), 212 -> ~25 us.
// R4-R6: MX-fp8 detour FAILED (unified-reg demand ~192 -> 2 waves/SIMD;
//   caps below demand spill to scratch). bf16 GEMM is the keeper.
// R7: fused reduce+gather. gemm plateau confirmed: LDS-pipe ~109 us +
//   barrier drains at 3.3 blocks/CU => ~200 us structural for this shape.
// R8: converts merged into ONE kernel (z: 4096 blocks x 8 elem/thread;
//   cb: one WAVE per row, no syncthreads, b128 stores). 4 -> 3 launches.

#define M_ROWS 16384
#define K_CODES 8192
#define DIM 512
#define BM 128
#define BN 128
#define BK 64
#define NT (K_CODES / BN)   // 64 ktiles
#define OUT0_SIZE (M_ROWS * DIM)
#define RG_BLOCKS 1024      // fused reduce+gather blocks (16 rows each)
#define ZBLK 4096           // convert: z blocks (16384*512 / (256*8))
#define CBBLK 2048          // convert: cb blocks (8192 rows / 4 waves)

typedef __bf16 bf16x8 __attribute__((ext_vector_type(8)));
typedef float f32x4 __attribute__((ext_vector_type(4)));

__device__ __forceinline__ unsigned short f2bf(float f) {
    unsigned int u = __builtin_bit_cast(unsigned int, f);
    u += 0x7FFFu + ((u >> 16) & 1u);   // RNE; inputs are finite
    return (unsigned short)(u >> 16);
}

// ---- kernel 1 (fused converts): z->bf16, cb->bf16 + row norms ----------
__global__ __launch_bounds__(256) void convert_all(const float* __restrict__ z,
                                                   const float* __restrict__ cb,
                                                   unsigned short* __restrict__ zb,
                                                   unsigned short* __restrict__ cbb,
                                                   float* __restrict__ enorm,
                                                   float* __restrict__ lossSlot) {
    const int tid = threadIdx.x;
    if (blockIdx.x == 0 && tid == 0) *lossSlot = 0.f;  // used 2 launches later
    if (blockIdx.x < ZBLK) {
        // z convert: 8 floats/thread, single b128 store
        size_t i = ((size_t)blockIdx.x * 256 + tid) * 8;
        float4 a = *(const float4*)(z + i);
        float4 b = *(const float4*)(z + i + 4);
        ushort4 lo, hi;
        lo.x = f2bf(a.x); lo.y = f2bf(a.y); lo.z = f2bf(a.z); lo.w = f2bf(a.w);
        hi.x = f2bf(b.x); hi.y = f2bf(b.y); hi.z = f2bf(b.z); hi.w = f2bf(b.w);
        *(ushort4*)(zb + i) = lo;
        *(ushort4*)(zb + i + 4) = hi;
    } else {
        // cb convert + norm: one wave per codebook row, wave-local reduce
        const int lane = tid & 63;
        const int w = tid >> 6;
        int k = (blockIdx.x - ZBLK) * 4 + w;
        const float* src = cb + (size_t)k * DIM + lane * 8;
        float4 a = *(const float4*)(src);
        float4 b = *(const float4*)(src + 4);
        ushort4 lo, hi;
        lo.x = f2bf(a.x); lo.y = f2bf(a.y); lo.z = f2bf(a.z); lo.w = f2bf(a.w);
        hi.x = f2bf(b.x); hi.y = f2bf(b.y); hi.z = f2bf(b.z); hi.w = f2bf(b.w);
        unsigned short* dst = cbb + (size_t)k * DIM + lane * 8;
        *(ushort4*)(dst) = lo;
        *(ushort4*)(dst + 4) = hi;
        float s = a.x * a.x + a.y * a.y + a.z * a.z + a.w * a.w
                + b.x * b.x + b.y * b.y + b.z * b.z + b.w * b.w;
        for (int m = 32; m; m >>= 1) s += __shfl_xor(s, m, 64);
        if (lane == 0) enorm[k] = s;
    }
}

// ---- kernel 2: MFMA GEMM + argmin epilogue (R3-proven, untouched) ------
__global__ __launch_bounds__(256, 2) void gemm_argmin(
    const unsigned short* __restrict__ zb, const unsigned short* __restrict__ cbb,
    const float* __restrict__ enorm, float* __restrict__ candV, int* __restrict__ candI) {
    __shared__ unsigned short As[BM * BK];   // 16 KB
    __shared__ unsigned short Bs[BN * BK];   // 16 KB
    __shared__ float Es[BN];
    __shared__ float cV[BM][2];
    __shared__ int cI[BM][2];

    const int tid = threadIdx.x;
    const int lane = tid & 63;
    const int w = tid >> 6;
    const int ktile = blockIdx.x;
    const int mtile = blockIdx.y;
    const int mbase = mtile * BM;
    const int nbase = ktile * BN;

    if (tid < BN) Es[tid] = enorm[nbase + tid];

    f32x4 acc[16];
#pragma unroll
    for (int i = 0; i < 16; ++i) acc[i] = (f32x4){0.f, 0.f, 0.f, 0.f};

    const int rA = lane >> 3;               // row offset within 8-row chunk
    const int jG = ((lane & 7) ^ rA) * 8;   // swizzled global 8-short chunk
    const int quad = lane >> 4;
    const int l15 = lane & 15;
    const int sw = (l15 & 7);               // read-side xor term = row&7
    const int rw = (w >> 1) * 64;           // wave's row quadrant
    const int cw = (w & 1) * 64;            // wave's col quadrant

    for (int dt = 0; dt < DIM; dt += BK) {
#pragma unroll
        for (int i = 0; i < 4; ++i) {
            int c = w * 4 + i;                       // 1KB chunk id (0..15)
            int row = c * 8 + rA;
            const unsigned short* ga = zb + (size_t)(mbase + row) * DIM + dt + jG;
            const unsigned short* gb = cbb + (size_t)(nbase + row) * DIM + dt + jG;
            unsigned short* la = As + c * 512 + lane * 8;
            unsigned short* lb = Bs + c * 512 + lane * 8;
            __builtin_amdgcn_global_load_lds((const __attribute__((address_space(1))) void*)ga,
                                             (__attribute__((address_space(3))) void*)la, 16, 0, 0);
            __builtin_amdgcn_global_load_lds((const __attribute__((address_space(1))) void*)gb,
                                             (__attribute__((address_space(3))) void*)lb, 16, 0, 0);
        }
        __syncthreads();
#pragma unroll
        for (int s = 0; s < 2; ++s) {
            // global chunk wanted: s*4 + quad; LDS chunk = (s*4+quad)^(row&7)
            const int jL = ((s * 4 + quad) ^ sw) * 8;
            bf16x8 af[4], bfr[4];
#pragma unroll
            for (int rf = 0; rf < 4; ++rf)
                af[rf] = *(const bf16x8*)(As + (rw + rf * 16 + l15) * BK + jL);
#pragma unroll
            for (int cf = 0; cf < 4; ++cf)
                bfr[cf] = *(const bf16x8*)(Bs + (cw + cf * 16 + l15) * BK + jL);
#pragma unroll
            for (int rf = 0; rf < 4; ++rf)
#pragma unroll
                for (int cf = 0; cf < 4; ++cf)
                    acc[rf * 4 + cf] = __builtin_amdgcn_mfma_f32_16x16x32_bf16(
                        af[rf], bfr[cf], acc[rf * 4 + cf], 0, 0, 0);
        }
        __syncthreads();
    }

    // epilogue: per-row argmin over this tile's 128 cols.
    // C/D layout: col = lane&15, row = quad*4 + reg.
#pragma unroll
    for (int rf = 0; rf < 4; ++rf) {
#pragma unroll
        for (int r = 0; r < 4; ++r) {
            float bv = 3.4e38f; int bi = 0x7fffffff;
#pragma unroll
            for (int cf = 0; cf < 4; ++cf) {
                int col = cw + cf * 16 + l15;
                float dist = Es[col] - 2.0f * acc[rf * 4 + cf][r];
                if (dist < bv) { bv = dist; bi = nbase + col; }  // strict <: lowest idx on tie
            }
#pragma unroll
            for (int m = 1; m < 16; m <<= 1) {
                float ov = __shfl_xor(bv, m, 64);
                int oi = __shfl_xor(bi, m, 64);
                if (ov < bv || (ov == bv && oi < bi)) { bv = ov; bi = oi; }
            }
            if (l15 == 0) {
                int rowT = rw + rf * 16 + quad * 4 + r;
                cV[rowT][w & 1] = bv;
                cI[rowT][w & 1] = bi;
            }
        }
    }
    __syncthreads();
    if (tid < BM) {
        float v0 = cV[tid][0], v1 = cV[tid][1];
        int i0 = cI[tid][0], i1 = cI[tid][1];
        bool take1 = (v1 < v0) || (v1 == v0 && i1 < i0);
        int row = mbase + tid;
        candV[(size_t)row * NT + ktile] = take1 ? v1 : v0;
        candI[(size_t)row * NT + ktile] = take1 ? i1 : i0;
    }
}

// ---- kernel 3 (fused): candidate reduce -> gather -> ST write -> loss --
// 1024 blocks x 16 rows; ONE loss atomic per block (atomic service rate
// ~80/us; 1024 spread over ~25 us kernel stays under pileup).
__global__ __launch_bounds__(256) void reduce_gather(
    const float* __restrict__ candV, const int* __restrict__ candI,
    const float* __restrict__ z, const float* __restrict__ cb,
    float* __restrict__ out) {
    __shared__ int sIdx[16];
    __shared__ float red[4];
    const int tid = threadIdx.x;
    const int lane = tid & 63;
    const int w = tid >> 6;
    const int rbase = blockIdx.x * 16;

#pragma unroll
    for (int j = 0; j < 4; ++j) {
        int row = rbase + w * 4 + j;
        float v = candV[(size_t)row * NT + lane];
        int i = candI[(size_t)row * NT + lane];
#pragma unroll
        for (int m = 1; m < 64; m <<= 1) {
            float ov = __shfl_xor(v, m, 64);
            int oi = __shfl_xor(i, m, 64);
            if (ov < v || (ov == v && oi < i)) { v = ov; i = oi; }
        }
        if (lane == 0) sIdx[w * 4 + j] = i;
    }
    __syncthreads();

    float lsum = 0.f;
#pragma unroll
    for (int j2 = 0; j2 < 8; ++j2) {
        int linear = j2 * 256 + tid;          // 0..2047 over 16 rows x 128 float4
        int rl = linear >> 7;                 // local row 0..15
        int sub = linear & 127;               // float4 slot in row
        int row = rbase + rl;
        int k = sIdx[rl];
        float4 zv = ((const float4*)(z + (size_t)row * DIM))[sub];
        float4 cv = ((const float4*)(cb + (size_t)k * DIM))[sub];
        float dx = cv.x - zv.x, dy = cv.y - zv.y;
        float dz2 = cv.z - zv.z, dw = cv.w - zv.w;
        float4 o = {zv.x + dx, zv.y + dy, zv.z + dz2, zv.w + dw};  // z + sg(zq-z)
        ((float4*)(out + (size_t)row * DIM))[sub] = o;
        lsum += dx * dx + dy * dy + dz2 * dz2 + dw * dw;
    }
    for (int m = 32; m; m >>= 1) lsum += __shfl_down(lsum, m, 64);
    if (lane == 0) red[w] = lsum;
    __syncthreads();
    if (tid == 0) {
        float t = (red[0] + red[1]) + (red[2] + red[3]);
        atomicAdd(out + OUT0_SIZE, t * (1.1f / (float)OUT0_SIZE));  // vq_loss = 1.1 * mean
    }
}

extern "C" void kernel_launch(void* const* d_in, const int* in_sizes, int n_in,
                              void* d_out, int out_size, void* d_ws, size_t ws_size,
                              hipStream_t stream) {
    const float* z = (const float*)d_in[0];     // 16*1024*512
    const float* cb = (const float*)d_in[1];    // 8192*512
    float* out = (float*)d_out;                 // 8388608 + 1
    char* ws = (char*)d_ws;

    // ws layout (bytes)
    unsigned short* zb  = (unsigned short*)(ws);              // 16,777,216
    unsigned short* cbb = (unsigned short*)(ws + 16777216);   //  8,388,608
    float* enorm        = (float*)(ws + 25165824);            //     32,768
    float* candV        = (float*)(ws + 25198592);            //  4,194,304
    int*   candI        = (int*)(ws + 29392896);              //  4,194,304

    convert_all<<<ZBLK + CBBLK, 256, 0, stream>>>(z, cb, zb, cbb, enorm, out + OUT0_SIZE);
    gemm_argmin<<<dim3(NT, M_ROWS / BM), 256, 0, stream>>>(zb, cbb, enorm, candV, candI);
    reduce_gather<<<RG_BLOCKS, 256, 0, stream>>>(candV, candI, z, cb, out);
}